// Round 11
// baseline (239.915 us; speedup 1.0000x reference)
//
#include <hip/hip_runtime.h>

// LIF neuron over [T, B, C, H, W] = [8, 32, 128, 32, 32] fp32.
// V_new = V + (-V/TAU + x_t); spike = (V_new>=1) - (V_new<=-1); hard reset.
//
// R1-R3:  single-chain, plain ld/st: 82 us rocprof, VGPR 24. 2.2 TB/s.
// R4-R6:  4-col MLP, nt ld/st. Harness 221.4 us (prev session).
// R7-R9:  register-preload attempts: compiler sinks cross-barrier
//         preloads every time (VGPR pinned 24-28). ~90-97 us.
//         Win kept: temporal loads halve FETCH to 64 MB (L3 retention).
// R10:    temporal stores beat nt by ~3%. Keep temporal.
// R11:    forced 8-deep MLP via global_load_lds + vmcnt(0) drain:
//         structure PROVEN, no improvement -> phase-drain dead end.
// R14:    4-col + temporal: 80.6 us / 2.50 TB/s, harness 231.1.
//         fillBufferAligned on same machine: 6.7 TB/s @ 9.9% occupancy
//         -> no systemic cap; low-occ + deep per-wave queue is a
//         proven-good operating point.
// R15:    8-col: lif_kernel dropped OUT of rocprof top-5 (<80.1 us,
//         est. 77-78 from the stable ~150 us harness offset; harness
//         228.1). Depth gradient real but flattening:
//         1-col 2.2 / 4-col 2.5 / 8-col ~2.6 TB/s.
// R17 (this): complete the depth sweep: NCOL=16 (Q=n4/16, 256 blocks,
//         1/CU). 16 back-to-back 1KB loads per wave per t. ~150-200
//         VGPR -> 2-3 waves/SIMD (~10% occ = fill's operating point)
//         but 16-deep queues (~32-48 KB/CU in flight).
//         Predict: 65-73 us / 2.8-3.1 TB/s if trend holds; 75-80 us ->
//         depth saturates at 8, revert; >85 us + VGPR>=250 or
//         FETCH/WRITE inflation -> spill, revert to NCOL=8.

#define T_STEPS 8
#define NCOL 16

typedef float vfloat4 __attribute__((ext_vector_type(4)));

struct StepOut { float V; float o; };

__device__ __forceinline__ StepOut lif_step(float V, float x) {
    const float TAU = (float)(5.0 / 3.0);  // fp32, matches np cast
    // Replicate reference op order exactly: neg, IEEE divide, add, add.
    float dv = (-V) / TAU + x;
    float Vn = V + dv;
    float o = (Vn >= 1.0f ? 1.0f : 0.0f) - (Vn <= -1.0f ? 1.0f : 0.0f);
    StepOut r;
    r.o = o;
    r.V = (o == 0.0f) ? Vn : 0.0f;  // o is exactly -1/0/+1
    return r;
}

__device__ __forceinline__ vfloat4 lif_step4(vfloat4& V, vfloat4 xt) {
    StepOut a = lif_step(V.x, xt.x);
    StepOut b = lif_step(V.y, xt.y);
    StepOut c = lif_step(V.z, xt.z);
    StepOut d = lif_step(V.w, xt.w);
    vfloat4 Vn, o;
    Vn.x = a.V; Vn.y = b.V; Vn.z = c.V; Vn.w = d.V;
    o.x = a.o;  o.y = b.o;  o.z = c.o;  o.w = d.o;
    V = Vn;
    return o;
}

__global__ __launch_bounds__(256) void lif_kernel(const vfloat4* __restrict__ x,
                                                  vfloat4* __restrict__ out,
                                                  int n4) {
    const int Q = n4 >> 4;  // columns per chain-slot (n4 = 2^20, /16 exact)
    int q = blockIdx.x * blockDim.x + threadIdx.x;
    if (q >= Q) return;

    const size_t s = (size_t)n4;

    // 16 independent V-chains per thread, Q-strided (wave-contiguous
    // 1 KB per stream per load). Full unroll -> all indices static,
    // everything in registers (watch VGPR_Count for spill).
    vfloat4 V[NCOL];
#pragma unroll
    for (int c = 0; c < NCOL; ++c) V[c] = (vfloat4)(0.f);

#pragma unroll
    for (int t = 0; t < T_STEPS; ++t) {
        const size_t base = (size_t)t * s + (size_t)q;

        // 16 independent TEMPORAL loads in one basic block -> issued
        // back-to-back (the R4/R15 mechanism): ~16 KB/wave in flight.
        vfloat4 xv[NCOL];
#pragma unroll
        for (int c = 0; c < NCOL; ++c) {
            xv[c] = x[base + (size_t)c * (size_t)Q];
        }

        vfloat4 o[NCOL];
#pragma unroll
        for (int c = 0; c < NCOL; ++c) {
            o[c] = lif_step4(V[c], xv[c]);
        }

        // TEMPORAL stores (R10: ~3% better than nt).
#pragma unroll
        for (int c = 0; c < NCOL; ++c) {
            out[base + (size_t)c * (size_t)Q] = o[c];
        }
    }
}

extern "C" void kernel_launch(void* const* d_in, const int* in_sizes, int n_in,
                              void* d_out, int out_size, void* d_ws, size_t ws_size,
                              hipStream_t stream) {
    const float* x = (const float*)d_in[0];
    float* out = (float*)d_out;

    int total = in_sizes[0];            // T*B*C*H*W = 33554432
    int n = total / T_STEPS;            // spatial elements per timestep
    int n4 = n / 4;                     // float4 groups = 1048576
    int Q = n4 / 16;                    // threads = 65536

    dim3 block(256);
    dim3 grid((Q + block.x - 1) / block.x);  // 256 blocks (1 per CU)
    lif_kernel<<<grid, block, 0, stream>>>((const vfloat4*)x, (vfloat4*)out, n4);
}

// Round 14
// 229.123 us; speedup vs baseline: 1.0471x; 1.0471x over previous
//
#include <hip/hip_runtime.h>

// LIF neuron over [T, B, C, H, W] = [8, 32, 128, 32, 32] fp32.
// V_new = V + (-V/TAU + x_t); spike = (V_new>=1) - (V_new<=-1); hard reset.
//
// R1-R3:  1-col: 82 us rocprof, 2.2 TB/s.
// R4-R10: 4-col + temporal ld/st: 80.6 us, 2.50 TB/s (nt stores -3%).
// R11:    global_load_lds forced 8-deep + phase drain: no change.
// R15:    8-col: est 77-78 us, ~2.65 TB/s. HARNESS BEST 228.1 us.
// R17:    16-col: 88 us, VGPR 88 (compiler caps depth), 2.3 TB/s.
//         Depth sweep complete: family identity waves/CU x NCOL = 64
//         (fixed in-flight budget); optimum = NCOL 8.
// R18:    full inline-asm 2-ahead pipeline (store-gating test): NaN.
//         Root cause: clang doesn't model VMEM latency of asm loads ->
//         regalloc inserts v_mov copies of load-dest registers BEFORE
//         the counted s_waitcnt asm (to satisfy "+v" ties / bank
//         rotation) -> reads in-flight registers. Store-gating
//         hypothesis remains UNTESTED (not falsified); testing it
//         needs a disasm-verified full-asm region, too risky blind.
// R19/R20 (this — R19 never ran, GPU acquisition timeout): restore
//         session-best passing kernel = R15 exactly (NCOL=8, temporal
//         loads [L3 retention: FETCH 128->64 MB], temporal stores
//         [+3% vs nt]). Re-anchors the graded metric. Known headroom
//         (fillBuffer 6.7 TB/s same-machine) remains, but all safe
//         levers are measured; remaining gap is the store-gating/
//         queueing mechanism requiring verified hand-asm.

#define T_STEPS 8
#define NCOL 8

typedef float vfloat4 __attribute__((ext_vector_type(4)));

struct StepOut { float V; float o; };

__device__ __forceinline__ StepOut lif_step(float V, float x) {
    const float TAU = (float)(5.0 / 3.0);  // fp32, matches np cast
    // Replicate reference op order exactly: neg, IEEE divide, add, add.
    float dv = (-V) / TAU + x;
    float Vn = V + dv;
    float o = (Vn >= 1.0f ? 1.0f : 0.0f) - (Vn <= -1.0f ? 1.0f : 0.0f);
    StepOut r;
    r.o = o;
    r.V = (o == 0.0f) ? Vn : 0.0f;  // o is exactly -1/0/+1
    return r;
}

__device__ __forceinline__ vfloat4 lif_step4(vfloat4& V, vfloat4 xt) {
    StepOut a = lif_step(V.x, xt.x);
    StepOut b = lif_step(V.y, xt.y);
    StepOut c = lif_step(V.z, xt.z);
    StepOut d = lif_step(V.w, xt.w);
    vfloat4 Vn, o;
    Vn.x = a.V; Vn.y = b.V; Vn.z = c.V; Vn.w = d.V;
    o.x = a.o;  o.y = b.o;  o.z = c.o;  o.w = d.o;
    V = Vn;
    return o;
}

__global__ __launch_bounds__(256) void lif_kernel(const vfloat4* __restrict__ x,
                                                  vfloat4* __restrict__ out,
                                                  int n4) {
    const int Q = n4 >> 3;  // columns per chain-slot (n4 divisible by 8)
    int q = blockIdx.x * blockDim.x + threadIdx.x;
    if (q >= Q) return;

    const size_t s = (size_t)n4;

    // 8 independent V-chains per thread, Q-strided (wave-contiguous
    // 1 KB per stream per load). All indices compile-time after unroll
    // -> everything stays in registers (no scratch).
    vfloat4 V[NCOL];
#pragma unroll
    for (int c = 0; c < NCOL; ++c) V[c] = (vfloat4)(0.f);

#pragma unroll
    for (int t = 0; t < T_STEPS; ++t) {
        const size_t base = (size_t)t * s + (size_t)q;

        // 8 independent TEMPORAL loads, same basic block -> compiler
        // issues them back-to-back (R4-mechanism): ~8 KB/wave in flight.
        vfloat4 xv[NCOL];
#pragma unroll
        for (int c = 0; c < NCOL; ++c) {
            xv[c] = x[base + (size_t)c * (size_t)Q];
        }

        vfloat4 o[NCOL];
#pragma unroll
        for (int c = 0; c < NCOL; ++c) {
            o[c] = lif_step4(V[c], xv[c]);
        }

        // TEMPORAL stores (R10: ~3% better than nt).
#pragma unroll
        for (int c = 0; c < NCOL; ++c) {
            out[base + (size_t)c * (size_t)Q] = o[c];
        }
    }
}

extern "C" void kernel_launch(void* const* d_in, const int* in_sizes, int n_in,
                              void* d_out, int out_size, void* d_ws, size_t ws_size,
                              hipStream_t stream) {
    const float* x = (const float*)d_in[0];
    float* out = (float*)d_out;

    int total = in_sizes[0];            // T*B*C*H*W = 33554432
    int n = total / T_STEPS;            // spatial elements per timestep
    int n4 = n / 4;                     // float4 groups = 1048576
    int Q = n4 / 8;                     // threads = 131072

    dim3 block(256);
    dim3 grid((Q + block.x - 1) / block.x);  // 512 blocks
    lif_kernel<<<grid, block, 0, stream>>>((const vfloat4*)x, (vfloat4*)out, n4);
}